// Round 2
// baseline (187.938 us; speedup 1.0000x reference)
//
#include <hip/hip_runtime.h>
#include <hip/hip_bf16.h>

// B=32, CQ=256, CC=3, COUT=256, H=W=32, HW=1024, INTER=128
//
// Math (verified rounds 0-5, absmax 0.031):
//   scores[i,j] = a[:,i]·ctx[:,j] + c_i (softmax-invariant const dropped)
//     a = M·Q + m0, M = Wk^T Wq (3x256)
//   fused = Wp·Q + G·cp + g0;  G = Wp·Wv (256x3), cp[t,i] = sum_j ctx[t,j]P[i,j]
//   resize 224->32 half-pixel = exact gather at (7y+3, 7x+3).
//
// R7: latency-bound fix (R6 counters: Occ 15.8%, VALUBusy 20%, MfmaUtil 2.6%,
// HBM 13% -- everything idle, 2 blocks/CU LDS-capped).
//   * i-tile 64->32, grid 1024, LDS 38.4 KB -> 4 blocks/CU (launch_bounds 256,4)
//   * ctx bilinear gather moved to sca_pre (128 parallel blocks -> ws, 512 KB,
//     L2-resident); sca_fused reads it as coalesced float4
//   * sca_pre blk1 (uncoalesced single-CU Wp*Wv, R5's 54us pattern) folded into
//     the 32 coalesced Wp-pack blocks via 32-lane shfl reduction; M split 4-way
//
// Workspace (float offsets):
#define WS_M     0        // M[3][256], m0[3] at 768
#define WS_G4    1024     // G4[o] = {G0,G1,G2,g0}
#define WS_BSUM  2048     // [32]
#define WS_BSSQ  2080     // [32]
#define WS_WPB   2176     // Wp bf16 fragment-packed [o_tile16][kt8][lane64][8]
#define WS_CTX   34944    // float4 {c0,c1,c2,0} [b 32][j 1024]  (512 KB)

typedef __attribute__((ext_vector_type(8))) short short8;
typedef __attribute__((ext_vector_type(4))) float floatx4;

__device__ inline unsigned short f2bf(float x) {
    unsigned u = __float_as_uint(x);
    return (unsigned short)((u + 0x7FFFu + ((u >> 16) & 1u)) >> 16);
}

// ---------- K0: weight precompute + Wp fragment-pack + ctx pre-gather ----------
// blocks 0..3: M = Wk^T Wq quarters; block 0 also bias + stats zero
// blocks 4..35: Wp bf16 pack + G = Wp*Wv via lane reduction
// blocks 36..163: ctx bilinear-gather -> ws (fully parallel, latency-hidden)
__global__ __launch_bounds__(256) void sca_pre(
    const float* __restrict__ Wq, const float* __restrict__ bq,
    const float* __restrict__ Wk, const float* __restrict__ bk,
    const float* __restrict__ Wv, const float* __restrict__ bv,
    const float* __restrict__ Wp, const float* __restrict__ bp,
    const float* __restrict__ ctxin, float* __restrict__ ws)
{
    int tid = threadIdx.x;
    int blk = blockIdx.x;
    if (blk < 4) {
        __shared__ float WkL[384];
        __shared__ float bqL[128];
        __shared__ float redM[4][64][3];
        int o0 = blk << 6;
        if (tid < 128) bqL[tid] = bq[tid];
        for (int idx = tid; idx < 384; idx += 256) WkL[idx] = Wk[idx];
        __syncthreads();
        int o64 = tid & 63, cg = tid >> 6;
        float m0v = 0.f, m1v = 0.f, m2v = 0.f;
        for (int c0 = cg * 32; c0 < cg * 32 + 32; c0 += 16) {
            float q[16];
#pragma unroll
            for (int j = 0; j < 16; ++j) q[j] = Wq[(c0 + j) * 256 + o0 + o64];
#pragma unroll
            for (int j = 0; j < 16; ++j) {
                int c = c0 + j;
                m0v = fmaf(WkL[c * 3 + 0], q[j], m0v);
                m1v = fmaf(WkL[c * 3 + 1], q[j], m1v);
                m2v = fmaf(WkL[c * 3 + 2], q[j], m2v);
            }
        }
        redM[cg][o64][0] = m0v; redM[cg][o64][1] = m1v; redM[cg][o64][2] = m2v;
        __syncthreads();
        if (tid < 64) {
            float r0 = redM[0][tid][0] + redM[1][tid][0] + redM[2][tid][0] + redM[3][tid][0];
            float r1 = redM[0][tid][1] + redM[1][tid][1] + redM[2][tid][1] + redM[3][tid][1];
            float r2 = redM[0][tid][2] + redM[1][tid][2] + redM[2][tid][2] + redM[3][tid][2];
            ws[WS_M + 0   + o0 + tid] = r0;
            ws[WS_M + 256 + o0 + tid] = r1;
            ws[WS_M + 512 + o0 + tid] = r2;
        }
        if (blk == 0) {
            if (tid < 3) {
                float s = 0.f;
                for (int c = 0; c < 128; ++c) s = fmaf(WkL[c * 3 + tid], bqL[c], s);
                ws[WS_M + 768 + tid] = s;
            }
            if (tid < 64) ws[WS_BSUM + tid] = 0.f;   // bsum[32]+bssq[32]
        }
    } else if (blk < 36) {
        __shared__ float WvL[768];
        __shared__ float bvL[256];
        for (int idx = tid; idx < 768; idx += 256) WvL[idx] = Wv[idx];
        bvL[tid] = bv[tid];
        __syncthreads();
        int idx = (blk - 4) * 2048 + tid * 8;       // flat [o][k] element index
        int o = idx >> 8;
        int kt = (tid & 31) >> 2, quad = tid & 3;
        const float4* s = (const float4*)(Wp + idx);
        float4 x0 = s[0], x1 = s[1];
        uint4 v;
        v.x = (unsigned)f2bf(x0.x) | ((unsigned)f2bf(x0.y) << 16);
        v.y = (unsigned)f2bf(x0.z) | ((unsigned)f2bf(x0.w) << 16);
        v.z = (unsigned)f2bf(x1.x) | ((unsigned)f2bf(x1.y) << 16);
        v.w = (unsigned)f2bf(x1.z) | ((unsigned)f2bf(x1.w) << 16);
        int slot = (((o >> 4) * 8 + kt) * 64) + quad * 16 + (o & 15);
        ((uint4*)((unsigned short*)(ws + WS_WPB)))[slot] = v;
        // G partials over this thread's 8 c; reduce over the 32 lanes sharing o
        int c0 = idx & 255;
        float xv[8] = {x0.x, x0.y, x0.z, x0.w, x1.x, x1.y, x1.z, x1.w};
        float g0 = 0.f, g1 = 0.f, g2 = 0.f, gb = 0.f;
#pragma unroll
        for (int j = 0; j < 8; ++j) {
            int c = c0 + j;
            g0 = fmaf(xv[j], WvL[c * 3 + 0], g0);
            g1 = fmaf(xv[j], WvL[c * 3 + 1], g1);
            g2 = fmaf(xv[j], WvL[c * 3 + 2], g2);
            gb = fmaf(xv[j], bvL[c], gb);
        }
#pragma unroll
        for (int off = 1; off < 32; off <<= 1) {
            g0 += __shfl_xor(g0, off);
            g1 += __shfl_xor(g1, off);
            g2 += __shfl_xor(g2, off);
            gb += __shfl_xor(gb, off);
        }
        if ((tid & 31) == 0)
            ((float4*)(ws + WS_G4))[o] = make_float4(g0, g1, g2, gb + bp[o]);
    } else {
        // ctx gather: one thread per (b, j)
        int g = (blk - 36) * 256 + tid;             // [0, 32768)
        int b = g >> 10, j = g & 1023;
        int y = j >> 5, x = j & 31;
        const float* src = ctxin + (size_t)b * 150528;
        int p = (7 * y + 3) * 224 + (7 * x + 3);
        ((float4*)(ws + WS_CTX))[g] =
            make_float4(src[p], src[p + 50176], src[p + 100352], 0.f);
    }
}

// ---------- K1: fused conv+attn+gemm. 1024 blocks = b(32) x i-tile(32 of 32).
// LDS 38.4 KB -> 4 blocks/CU. Phases: ctx copy (coalesced) + Ms; Q load +
// a-partials + bf16 pack -> swizzled LDS frags; MFMA K-loop; softmax+cp
// (8 lanes/query); epilogue rank-3 + bias + stats + store. ----------
__global__ __launch_bounds__(256, 4) void sca_fused(const float* __restrict__ Q,
                                                    float* __restrict__ ws,
                                                    float* __restrict__ out)
{
    __shared__ float Ms[771];
    __shared__ float4 cs[1024];           // ctx {c0,c1,c2,0}
    __shared__ uint4 QL[1024];            // 32 rows x 32 16B-groups, XOR-swizzled
    __shared__ float red[4][8][12];       // [wave][iq][t*4+e]
    __shared__ float4 av4[32];
    __shared__ float4 cps[32];
    int tid = threadIdx.x;
    int blk = blockIdx.x;
    int b  = blk >> 5;
    int i0 = (blk & 31) << 5;

    // ctx copy from pre-gathered ws (coalesced float4; L2-resident, 16 KB/b)
    {
        const float4* cg4 = ((const float4*)(ws + WS_CTX)) + ((size_t)b << 10);
#pragma unroll
        for (int s4 = 0; s4 < 4; ++s4) {
            int j = s4 * 256 + tid;
            cs[j] = cg4[j];
        }
    }
    for (int idx = tid; idx < 771; idx += 256) Ms[idx] = ws[WS_M + idx];
    __syncthreads();

    // ---- Q load + a-partials + bf16 pack ----
    int iq = tid & 7, kg = tid >> 3;      // 4 consecutive i x 8 consecutive k
    const float* Qp = Q + ((size_t)b << 18) + ((size_t)(kg * 8) << 10) + i0 + iq * 4;
    float a00=0.f,a01=0.f,a02=0.f,a03=0.f;
    float a10=0.f,a11=0.f,a12=0.f,a13=0.f;
    float a20=0.f,a21=0.f,a22=0.f,a23=0.f;
    unsigned pk[4][4];                     // [e][pair]: bf16 of k = kg*8 + 2*pair(+1)
#pragma unroll
    for (int s = 0; s < 8; ++s) {
        float4 qv = *(const float4*)(Qp + ((size_t)s << 10));
        int c = kg * 8 + s;
        float m0 = Ms[c], m1 = Ms[256 + c], m2 = Ms[512 + c];
        a00 = fmaf(m0, qv.x, a00); a01 = fmaf(m0, qv.y, a01); a02 = fmaf(m0, qv.z, a02); a03 = fmaf(m0, qv.w, a03);
        a10 = fmaf(m1, qv.x, a10); a11 = fmaf(m1, qv.y, a11); a12 = fmaf(m1, qv.z, a12); a13 = fmaf(m1, qv.w, a13);
        a20 = fmaf(m2, qv.x, a20); a21 = fmaf(m2, qv.y, a21); a22 = fmaf(m2, qv.z, a22); a23 = fmaf(m2, qv.w, a23);
        unsigned h0 = f2bf(qv.x), h1 = f2bf(qv.y), h2 = f2bf(qv.z), h3 = f2bf(qv.w);
        int j = s >> 1;
        if (s & 1) {
            pk[0][j] |= h0 << 16; pk[1][j] |= h1 << 16;
            pk[2][j] |= h2 << 16; pk[3][j] |= h3 << 16;
        } else {
            pk[0][j] = h0; pk[1][j] = h1; pk[2][j] = h2; pk[3][j] = h3;
        }
    }
    // B-fragments into swizzled LDS: row = local i, 16B-group g = k-octet = kg.
    // swizzle s=(row^(row>>3))&7 on low 3 bits of g: conflict-free writes+reads.
#pragma unroll
    for (int e = 0; e < 4; ++e) {
        int row = iq * 4 + e;
        int sw = (row ^ (row >> 3)) & 7;
        int gs = (kg & 24) | ((kg ^ sw) & 7);
        QL[row * 32 + gs] = make_uint4(pk[e][0], pk[e][1], pk[e][2], pk[e][3]);
    }
    // a-reduction over kg low bits (lane bits 3,4,5), then cross-wave via LDS
    a00 += __shfl_xor(a00,8); a00 += __shfl_xor(a00,16); a00 += __shfl_xor(a00,32);
    a01 += __shfl_xor(a01,8); a01 += __shfl_xor(a01,16); a01 += __shfl_xor(a01,32);
    a02 += __shfl_xor(a02,8); a02 += __shfl_xor(a02,16); a02 += __shfl_xor(a02,32);
    a03 += __shfl_xor(a03,8); a03 += __shfl_xor(a03,16); a03 += __shfl_xor(a03,32);
    a10 += __shfl_xor(a10,8); a10 += __shfl_xor(a10,16); a10 += __shfl_xor(a10,32);
    a11 += __shfl_xor(a11,8); a11 += __shfl_xor(a11,16); a11 += __shfl_xor(a11,32);
    a12 += __shfl_xor(a12,8); a12 += __shfl_xor(a12,16); a12 += __shfl_xor(a12,32);
    a13 += __shfl_xor(a13,8); a13 += __shfl_xor(a13,16); a13 += __shfl_xor(a13,32);
    a20 += __shfl_xor(a20,8); a20 += __shfl_xor(a20,16); a20 += __shfl_xor(a20,32);
    a21 += __shfl_xor(a21,8); a21 += __shfl_xor(a21,16); a21 += __shfl_xor(a21,32);
    a22 += __shfl_xor(a22,8); a22 += __shfl_xor(a22,16); a22 += __shfl_xor(a22,32);
    a23 += __shfl_xor(a23,8); a23 += __shfl_xor(a23,16); a23 += __shfl_xor(a23,32);
    int lane = tid & 63, w = tid >> 6;
    if (lane < 8) {
        red[w][lane][0]=a00; red[w][lane][1]=a01; red[w][lane][2] =a02; red[w][lane][3] =a03;
        red[w][lane][4]=a10; red[w][lane][5]=a11; red[w][lane][6] =a12; red[w][lane][7] =a13;
        red[w][lane][8]=a20; red[w][lane][9]=a21; red[w][lane][10]=a22; red[w][lane][11]=a23;
    }
    __syncthreads();
    if (tid < 32) {
        int iqq = tid >> 2, e = tid & 3;
        float r0 = red[0][iqq][0+e] + red[1][iqq][0+e] + red[2][iqq][0+e] + red[3][iqq][0+e] + Ms[768];
        float r1 = red[0][iqq][4+e] + red[1][iqq][4+e] + red[2][iqq][4+e] + red[3][iqq][4+e] + Ms[769];
        float r2 = red[0][iqq][8+e] + red[1][iqq][8+e] + red[2][iqq][8+e] + red[3][iqq][8+e] + Ms[770];
        av4[tid] = make_float4(r0, r1, r2, 0.f);
    }
    __syncthreads();

    // ---- MFMA K-loop: wave w covers o = w*64..w*64+63, all 32 i of block ----
    int m = lane & 15, quad = lane >> 4;
    const short8* Apack = (const short8*)((const unsigned short*)(ws + WS_WPB));
    const short8* QLs = (const short8*)QL;
    floatx4 acc[4][2] = {};
#pragma unroll
    for (int kt = 0; kt < 8; ++kt) {
        short8 af[4], bf[2];
#pragma unroll
        for (int t = 0; t < 4; ++t)
            af[t] = Apack[((w * 4 + t) * 8 + kt) * 64 + lane];
#pragma unroll
        for (int t = 0; t < 2; ++t) {
            int row = t * 16 + m;
            int sw = (row ^ (row >> 3)) & 7;
            int g = kt * 4 + quad;
            int gs = (g & 24) | ((g ^ sw) & 7);
            bf[t] = QLs[row * 32 + gs];
        }
#pragma unroll
        for (int to = 0; to < 4; ++to)
#pragma unroll
            for (int ti = 0; ti < 2; ++ti)
                acc[to][ti] = __builtin_amdgcn_mfma_f32_16x16x32_bf16(
                    af[to], bf[ti], acc[to][ti], 0, 0, 0);
    }

    // ---- softmax + cp (8 lanes per query i, single pass, analytic shift) ----
    {
        int qi = tid >> 3, sl = tid & 7;
        float4 a = av4[qi];
        // |ctx| <= ~5.3 over N(0,1); shift 6*|a|_1 keeps exp args in [-~30, 0].
        float sh = 6.0f * (fabsf(a.x) + fabsf(a.y) + fabsf(a.z));
        float d = 0.f, s0 = 0.f, s1 = 0.f, s2 = 0.f;
#pragma unroll 4
        for (int jj = 0; jj < 128; ++jj) {
            float4 c = cs[(jj << 3) + sl];
            float sc = fmaf(a.x, c.x, fmaf(a.y, c.y, a.z * c.z));
            float e = __expf(sc - sh);
            d += e;
            s0 = fmaf(e, c.x, s0);
            s1 = fmaf(e, c.y, s1);
            s2 = fmaf(e, c.z, s2);
        }
        d  += __shfl_xor(d, 1);  d  += __shfl_xor(d, 2);  d  += __shfl_xor(d, 4);
        s0 += __shfl_xor(s0, 1); s0 += __shfl_xor(s0, 2); s0 += __shfl_xor(s0, 4);
        s1 += __shfl_xor(s1, 1); s1 += __shfl_xor(s1, 2); s1 += __shfl_xor(s1, 4);
        s2 += __shfl_xor(s2, 1); s2 += __shfl_xor(s2, 2); s2 += __shfl_xor(s2, 4);
        if (sl == 0) {
            float inv = 1.0f / d;
            cps[qi] = make_float4(s0 * inv, s1 * inv, s2 * inv, 0.f);
        }
    }
    __syncthreads();

    // ---- epilogue: rank-3 + bias, store, GroupNorm partial stats ----
    const floatx4* G4 = (const floatx4*)(ws + WS_G4);
    float4 cpv[2];
#pragma unroll
    for (int ti = 0; ti < 2; ++ti) cpv[ti] = cps[ti * 16 + m];
    float lsum = 0.f, lssq = 0.f;
#pragma unroll
    for (int to = 0; to < 4; ++to)
#pragma unroll
        for (int r = 0; r < 4; ++r) {
            int o = w * 64 + to * 16 + quad * 4 + r;
            floatx4 g = G4[o];
            float* orow = out + (((size_t)(b * 256 + o)) << 10) + i0 + m;
#pragma unroll
            for (int ti = 0; ti < 2; ++ti) {
                float v = acc[to][ti][r]
                        + g[0] * cpv[ti].x + g[1] * cpv[ti].y + g[2] * cpv[ti].z + g[3];
                orow[ti * 16] = v;
                lsum += v; lssq = fmaf(v, v, lssq);
            }
        }
#pragma unroll
    for (int off = 32; off > 0; off >>= 1) {
        lsum += __shfl_down(lsum, off);
        lssq += __shfl_down(lssq, off);
    }
    if (lane == 0) {
        atomicAdd(ws + WS_BSUM + b, lsum);
        atomicAdd(ws + WS_BSSQ + b, lssq);
    }
}

// ---------- K2: GroupNorm(1 group) normalize in place ----------
__global__ __launch_bounds__(256) void sca_norm(float* __restrict__ out,
                                                const float* __restrict__ ws,
                                                const float* __restrict__ gamma,
                                                const float* __restrict__ beta)
{
    size_t idx = (size_t)blockIdx.x * 256 + threadIdx.x;  // float4 index
    float4 v = ((const float4*)out)[idx];
    size_t base = idx << 2;
    int b = (int)(base >> 18);
    int o = (int)((base >> 10) & 255);
    const float inv_n = 1.0f / 262144.0f;
    float mean = ws[WS_BSUM + b] * inv_n;
    float var  = fmaf(ws[WS_BSSQ + b], inv_n, -mean * mean);
    float rs = rsqrtf(var + 1e-5f);
    float ga = gamma[o] * rs;
    float be = fmaf(-mean, ga, beta[o]);
    v.x = fmaf(v.x, ga, be);
    v.y = fmaf(v.y, ga, be);
    v.z = fmaf(v.z, ga, be);
    v.w = fmaf(v.w, ga, be);
    ((float4*)out)[idx] = v;
}

extern "C" void kernel_launch(void* const* d_in, const int* in_sizes, int n_in,
                              void* d_out, int out_size, void* d_ws, size_t ws_size,
                              hipStream_t stream)
{
    const float* Q     = (const float*)d_in[0];
    const float* ctxf  = (const float*)d_in[1];
    const float* Wq    = (const float*)d_in[2];
    const float* bq    = (const float*)d_in[3];
    const float* Wk    = (const float*)d_in[4];
    const float* bk    = (const float*)d_in[5];
    const float* Wv    = (const float*)d_in[6];
    const float* bv    = (const float*)d_in[7];
    const float* Wp    = (const float*)d_in[8];
    const float* bp    = (const float*)d_in[9];
    const float* gamma = (const float*)d_in[10];
    const float* beta  = (const float*)d_in[11];
    float* ws  = (float*)d_ws;
    float* out = (float*)d_out;

    sca_pre  <<<164,  256, 0, stream>>>(Wq, bq, Wk, bk, Wv, bv, Wp, bp, ctxf, ws);
    sca_fused<<<1024, 256, 0, stream>>>(Q, ws, out);
    sca_norm <<<8192, 256, 0, stream>>>(out, ws, gamma, beta);
}

// Round 3
// 187.495 us; speedup vs baseline: 1.0024x; 1.0024x over previous
//
#include <hip/hip_runtime.h>
#include <hip/hip_bf16.h>

// B=32, CQ=256, CC=3, COUT=256, H=W=32, HW=1024, INTER=128
//
// Math (verified rounds 0-5, absmax 0.031):
//   scores[i,j] = a[:,i]·ctx[:,j] + c_i (softmax-invariant const dropped)
//     a = M·Q + m0, M = Wk^T Wq (3x256)
//   fused = Wp·Q + G·cp + g0;  G = Wp·Wv (256x3), cp[t,i] = sum_j ctx[t,j]P[i,j]
//   resize 224->32 half-pixel = exact gather at (7y+3, 7x+3).
//
// R8: R7 post-mortem -- halving i-tile doubled per-block fixed overhead
// (ctx+Ms copy, barriers, full Wp re-read) and regressed 60->76us. Revert to
// i-tile=64 (512 blocks) but lift R6's 2-block/CU LDS cap to 4 by staging K
// in two 128-row halves through ONE 16 KB QL buffer (LDS 57.9 -> 39.0 KB),
// red/cps union. launch_bounds(256,4) caps VGPR at 128.
//
// Workspace (float offsets):
#define WS_M     0        // M[3][256], m0[3] at 768
#define WS_G4    1024     // G4[o] = {G0,G1,G2,g0}
#define WS_BSUM  2048     // [32]
#define WS_BSSQ  2080     // [32]
#define WS_WPB   2176     // Wp bf16 fragment-packed [o_tile16][kt8][lane64][8]
#define WS_CTX   34944    // float4 {c0,c1,c2,0} [b 32][j 1024]  (512 KB)

typedef __attribute__((ext_vector_type(8))) short short8;
typedef __attribute__((ext_vector_type(4))) float floatx4;

__device__ inline unsigned short f2bf(float x) {
    unsigned u = __float_as_uint(x);
    return (unsigned short)((u + 0x7FFFu + ((u >> 16) & 1u)) >> 16);
}

// ---------- K0: weight precompute + Wp fragment-pack + ctx pre-gather ----------
// blocks 0..3: M = Wk^T Wq quarters; block 0 also bias + stats zero
// blocks 4..35: Wp bf16 pack + G = Wp*Wv via lane reduction
// blocks 36..163: ctx bilinear-gather -> ws (fully parallel, latency-hidden)
__global__ __launch_bounds__(256) void sca_pre(
    const float* __restrict__ Wq, const float* __restrict__ bq,
    const float* __restrict__ Wk, const float* __restrict__ bk,
    const float* __restrict__ Wv, const float* __restrict__ bv,
    const float* __restrict__ Wp, const float* __restrict__ bp,
    const float* __restrict__ ctxin, float* __restrict__ ws)
{
    int tid = threadIdx.x;
    int blk = blockIdx.x;
    if (blk < 4) {
        __shared__ float WkL[384];
        __shared__ float bqL[128];
        __shared__ float redM[4][64][3];
        int o0 = blk << 6;
        if (tid < 128) bqL[tid] = bq[tid];
        for (int idx = tid; idx < 384; idx += 256) WkL[idx] = Wk[idx];
        __syncthreads();
        int o64 = tid & 63, cg = tid >> 6;
        float m0v = 0.f, m1v = 0.f, m2v = 0.f;
        for (int c0 = cg * 32; c0 < cg * 32 + 32; c0 += 16) {
            float q[16];
#pragma unroll
            for (int j = 0; j < 16; ++j) q[j] = Wq[(c0 + j) * 256 + o0 + o64];
#pragma unroll
            for (int j = 0; j < 16; ++j) {
                int c = c0 + j;
                m0v = fmaf(WkL[c * 3 + 0], q[j], m0v);
                m1v = fmaf(WkL[c * 3 + 1], q[j], m1v);
                m2v = fmaf(WkL[c * 3 + 2], q[j], m2v);
            }
        }
        redM[cg][o64][0] = m0v; redM[cg][o64][1] = m1v; redM[cg][o64][2] = m2v;
        __syncthreads();
        if (tid < 64) {
            float r0 = redM[0][tid][0] + redM[1][tid][0] + redM[2][tid][0] + redM[3][tid][0];
            float r1 = redM[0][tid][1] + redM[1][tid][1] + redM[2][tid][1] + redM[3][tid][1];
            float r2 = redM[0][tid][2] + redM[1][tid][2] + redM[2][tid][2] + redM[3][tid][2];
            ws[WS_M + 0   + o0 + tid] = r0;
            ws[WS_M + 256 + o0 + tid] = r1;
            ws[WS_M + 512 + o0 + tid] = r2;
        }
        if (blk == 0) {
            if (tid < 3) {
                float s = 0.f;
                for (int c = 0; c < 128; ++c) s = fmaf(WkL[c * 3 + tid], bqL[c], s);
                ws[WS_M + 768 + tid] = s;
            }
            if (tid < 64) ws[WS_BSUM + tid] = 0.f;   // bsum[32]+bssq[32]
        }
    } else if (blk < 36) {
        __shared__ float WvL[768];
        __shared__ float bvL[256];
        for (int idx = tid; idx < 768; idx += 256) WvL[idx] = Wv[idx];
        bvL[tid] = bv[tid];
        __syncthreads();
        int idx = (blk - 4) * 2048 + tid * 8;       // flat [o][k] element index
        int o = idx >> 8;
        int kt = (tid & 31) >> 2, quad = tid & 3;
        const float4* s = (const float4*)(Wp + idx);
        float4 x0 = s[0], x1 = s[1];
        uint4 v;
        v.x = (unsigned)f2bf(x0.x) | ((unsigned)f2bf(x0.y) << 16);
        v.y = (unsigned)f2bf(x0.z) | ((unsigned)f2bf(x0.w) << 16);
        v.z = (unsigned)f2bf(x1.x) | ((unsigned)f2bf(x1.y) << 16);
        v.w = (unsigned)f2bf(x1.z) | ((unsigned)f2bf(x1.w) << 16);
        int slot = (((o >> 4) * 8 + kt) * 64) + quad * 16 + (o & 15);
        ((uint4*)((unsigned short*)(ws + WS_WPB)))[slot] = v;
        // G partials over this thread's 8 c; reduce over the 32 lanes sharing o
        int c0 = idx & 255;
        float xv[8] = {x0.x, x0.y, x0.z, x0.w, x1.x, x1.y, x1.z, x1.w};
        float g0 = 0.f, g1 = 0.f, g2 = 0.f, gb = 0.f;
#pragma unroll
        for (int j = 0; j < 8; ++j) {
            int c = c0 + j;
            g0 = fmaf(xv[j], WvL[c * 3 + 0], g0);
            g1 = fmaf(xv[j], WvL[c * 3 + 1], g1);
            g2 = fmaf(xv[j], WvL[c * 3 + 2], g2);
            gb = fmaf(xv[j], bvL[c], gb);
        }
#pragma unroll
        for (int off = 1; off < 32; off <<= 1) {
            g0 += __shfl_xor(g0, off);
            g1 += __shfl_xor(g1, off);
            g2 += __shfl_xor(g2, off);
            gb += __shfl_xor(gb, off);
        }
        if ((tid & 31) == 0)
            ((float4*)(ws + WS_G4))[o] = make_float4(g0, g1, g2, gb + bp[o]);
    } else {
        // ctx gather: one thread per (b, j)
        int g = (blk - 36) * 256 + tid;             // [0, 32768)
        int b = g >> 10, j = g & 1023;
        int y = j >> 5, x = j & 31;
        const float* src = ctxin + (size_t)b * 150528;
        int p = (7 * y + 3) * 224 + (7 * x + 3);
        ((float4*)(ws + WS_CTX))[g] =
            make_float4(src[p], src[p + 50176], src[p + 100352], 0.f);
    }
}

// ---------- K1: fused conv+attn+gemm. 512 blocks = b(32) x i-tile(16 of 64).
// LDS 39.0 KB -> 4 blocks/CU. K staged in two 128-row halves through one
// 16 KB QL buffer. Phases: A ctx/Ms + Q-h0 issue; B consume h0 -> QL; C MFMA
// h0 + issue h1; D consume h1 -> QL; E MFMA h1; reduce; softmax; epilogue.
__global__ __launch_bounds__(256, 4) void sca_fused(const float* __restrict__ Q,
                                                    float* __restrict__ ws,
                                                    float* __restrict__ out)
{
    __shared__ float Ms[771];
    __shared__ float4 cs[1024];           // ctx {c0,c1,c2,0}
    __shared__ uint4 QL[1024];            // 64 rows x 16 16B-groups, XOR-swizzled
    __shared__ float red[4][16][12];      // [wave][iq][t*4+e]; aliased by cps
    __shared__ float4 av4[64];
    float4* cps = (float4*)red;           // cps[64] reuses red after av4 done

    int tid = threadIdx.x;
    int blk = blockIdx.x;
    int b  = blk >> 4;
    int i0 = (blk & 15) << 6;
    int lane = tid & 63, w = tid >> 6;
    int iq = tid & 15, kg = tid >> 4;     // 4 consecutive i x 16 k-groups (8 k each)

    // ---- Phase A: issue Q-h0 loads first (HBM latency), then ctx/Ms staging ----
    const float* Qp = Q + ((size_t)b << 18) + ((size_t)(kg * 8) << 10) + i0 + iq * 4;
    float4 qv[8];
#pragma unroll
    for (int s = 0; s < 8; ++s) qv[s] = *(const float4*)(Qp + ((size_t)s << 10));
    {
        const float4* cg4 = ((const float4*)(ws + WS_CTX)) + ((size_t)b << 10);
#pragma unroll
        for (int s4 = 0; s4 < 4; ++s4) cs[s4 * 256 + tid] = cg4[s4 * 256 + tid];
    }
    for (int idx = tid; idx < 771; idx += 256) Ms[idx] = ws[WS_M + idx];
    __syncthreads();

    // ---- Phase B: consume h0 (k=0..127): a-partials + bf16 pack -> QL ----
    float a00=0.f,a01=0.f,a02=0.f,a03=0.f;
    float a10=0.f,a11=0.f,a12=0.f,a13=0.f;
    float a20=0.f,a21=0.f,a22=0.f,a23=0.f;
    unsigned pk[4][4];
#pragma unroll
    for (int s = 0; s < 8; ++s) {
        float4 q = qv[s];
        int c = kg * 8 + s;
        float m0 = Ms[c], m1 = Ms[256 + c], m2 = Ms[512 + c];
        a00 = fmaf(m0, q.x, a00); a01 = fmaf(m0, q.y, a01); a02 = fmaf(m0, q.z, a02); a03 = fmaf(m0, q.w, a03);
        a10 = fmaf(m1, q.x, a10); a11 = fmaf(m1, q.y, a11); a12 = fmaf(m1, q.z, a12); a13 = fmaf(m1, q.w, a13);
        a20 = fmaf(m2, q.x, a20); a21 = fmaf(m2, q.y, a21); a22 = fmaf(m2, q.z, a22); a23 = fmaf(m2, q.w, a23);
        unsigned h0 = f2bf(q.x), h1 = f2bf(q.y), h2 = f2bf(q.z), h3 = f2bf(q.w);
        int j = s >> 1;
        if (s & 1) {
            pk[0][j] |= h0 << 16; pk[1][j] |= h1 << 16;
            pk[2][j] |= h2 << 16; pk[3][j] |= h3 << 16;
        } else {
            pk[0][j] = h0; pk[1][j] = h1; pk[2][j] = h2; pk[3][j] = h3;
        }
    }
    // row = local i; group g = kg (8 k = 16 B). swizzle on low 3 bits of g.
#pragma unroll
    for (int e = 0; e < 4; ++e) {
        int row = iq * 4 + e;
        int sw = (row ^ (row >> 3)) & 7;
        int gs = (kg & 8) | ((kg ^ sw) & 7);
        QL[row * 16 + gs] = make_uint4(pk[e][0], pk[e][1], pk[e][2], pk[e][3]);
    }
    __syncthreads();

    // ---- Phase C: MFMA over h0 (global kt 0..3), then issue h1 loads ----
    int m = lane & 15, quad = lane >> 4;
    const short8* Apack = (const short8*)((const unsigned short*)(ws + WS_WPB));
    const short8* QLs = (const short8*)QL;
    floatx4 acc[4][4] = {};
#pragma unroll
    for (int kt = 0; kt < 4; ++kt) {
        short8 af[4], bf[4];
#pragma unroll
        for (int t = 0; t < 4; ++t)
            af[t] = Apack[((w * 4 + t) * 8 + kt) * 64 + lane];
#pragma unroll
        for (int t = 0; t < 4; ++t) {
            int row = t * 16 + m;
            int sw = (row ^ (row >> 3)) & 7;
            int g = kt * 4 + quad;
            int gs = (g & 8) | ((g ^ sw) & 7);
            bf[t] = QLs[row * 16 + gs];
        }
#pragma unroll
        for (int to = 0; to < 4; ++to)
#pragma unroll
            for (int ti = 0; ti < 4; ++ti)
                acc[to][ti] = __builtin_amdgcn_mfma_f32_16x16x32_bf16(
                    af[to], bf[ti], acc[to][ti], 0, 0, 0);
    }
#pragma unroll
    for (int s = 0; s < 8; ++s) qv[s] = *(const float4*)(Qp + ((size_t)(s + 128) << 10));
    __syncthreads();                       // all QL-h0 reads complete

    // ---- Phase D: consume h1 (k=128..255): a-partials + pack -> QL ----
#pragma unroll
    for (int s = 0; s < 8; ++s) {
        float4 q = qv[s];
        int c = 128 + kg * 8 + s;
        float m0 = Ms[c], m1 = Ms[256 + c], m2 = Ms[512 + c];
        a00 = fmaf(m0, q.x, a00); a01 = fmaf(m0, q.y, a01); a02 = fmaf(m0, q.z, a02); a03 = fmaf(m0, q.w, a03);
        a10 = fmaf(m1, q.x, a10); a11 = fmaf(m1, q.y, a11); a12 = fmaf(m1, q.z, a12); a13 = fmaf(m1, q.w, a13);
        a20 = fmaf(m2, q.x, a20); a21 = fmaf(m2, q.y, a21); a22 = fmaf(m2, q.z, a22); a23 = fmaf(m2, q.w, a23);
        unsigned h0 = f2bf(q.x), h1 = f2bf(q.y), h2 = f2bf(q.z), h3 = f2bf(q.w);
        int j = s >> 1;
        if (s & 1) {
            pk[0][j] |= h0 << 16; pk[1][j] |= h1 << 16;
            pk[2][j] |= h2 << 16; pk[3][j] |= h3 << 16;
        } else {
            pk[0][j] = h0; pk[1][j] = h1; pk[2][j] = h2; pk[3][j] = h3;
        }
    }
#pragma unroll
    for (int e = 0; e < 4; ++e) {
        int row = iq * 4 + e;
        int sw = (row ^ (row >> 3)) & 7;
        int gs = (kg & 8) | ((kg ^ sw) & 7);
        QL[row * 16 + gs] = make_uint4(pk[e][0], pk[e][1], pk[e][2], pk[e][3]);
    }
    __syncthreads();

    // ---- Phase E: MFMA over h1 (global kt 4..7) ----
#pragma unroll
    for (int kt = 0; kt < 4; ++kt) {
        short8 af[4], bf[4];
#pragma unroll
        for (int t = 0; t < 4; ++t)
            af[t] = Apack[((w * 4 + t) * 8 + (kt + 4)) * 64 + lane];
#pragma unroll
        for (int t = 0; t < 4; ++t) {
            int row = t * 16 + m;
            int sw = (row ^ (row >> 3)) & 7;
            int g = kt * 4 + quad;
            int gs = (g & 8) | ((g ^ sw) & 7);
            bf[t] = QLs[row * 16 + gs];
        }
#pragma unroll
        for (int to = 0; to < 4; ++to)
#pragma unroll
            for (int ti = 0; ti < 4; ++ti)
                acc[to][ti] = __builtin_amdgcn_mfma_f32_16x16x32_bf16(
                    af[to], bf[ti], acc[to][ti], 0, 0, 0);
    }

    // ---- a-reduction over kg: shfl within wave, LDS across waves ----
    a00 += __shfl_xor(a00,16); a00 += __shfl_xor(a00,32);
    a01 += __shfl_xor(a01,16); a01 += __shfl_xor(a01,32);
    a02 += __shfl_xor(a02,16); a02 += __shfl_xor(a02,32);
    a03 += __shfl_xor(a03,16); a03 += __shfl_xor(a03,32);
    a10 += __shfl_xor(a10,16); a10 += __shfl_xor(a10,32);
    a11 += __shfl_xor(a11,16); a11 += __shfl_xor(a11,32);
    a12 += __shfl_xor(a12,16); a12 += __shfl_xor(a12,32);
    a13 += __shfl_xor(a13,16); a13 += __shfl_xor(a13,32);
    a20 += __shfl_xor(a20,16); a20 += __shfl_xor(a20,32);
    a21 += __shfl_xor(a21,16); a21 += __shfl_xor(a21,32);
    a22 += __shfl_xor(a22,16); a22 += __shfl_xor(a22,32);
    a23 += __shfl_xor(a23,16); a23 += __shfl_xor(a23,32);
    if (lane < 16) {
        red[w][lane][0]=a00; red[w][lane][1]=a01; red[w][lane][2] =a02; red[w][lane][3] =a03;
        red[w][lane][4]=a10; red[w][lane][5]=a11; red[w][lane][6] =a12; red[w][lane][7] =a13;
        red[w][lane][8]=a20; red[w][lane][9]=a21; red[w][lane][10]=a22; red[w][lane][11]=a23;
    }
    __syncthreads();
    if (tid < 64) {
        int iqq = tid >> 2, e = tid & 3;
        float r0 = red[0][iqq][0+e] + red[1][iqq][0+e] + red[2][iqq][0+e] + red[3][iqq][0+e] + Ms[768];
        float r1 = red[0][iqq][4+e] + red[1][iqq][4+e] + red[2][iqq][4+e] + red[3][iqq][4+e] + Ms[769];
        float r2 = red[0][iqq][8+e] + red[1][iqq][8+e] + red[2][iqq][8+e] + red[3][iqq][8+e] + Ms[770];
        av4[tid] = make_float4(r0, r1, r2, 0.f);
    }
    __syncthreads();

    // ---- softmax + cp (4 lanes per query i, single pass, analytic shift) ----
    {
        int qi = tid >> 2, sl = tid & 3;
        float4 a = av4[qi];
        // |ctx| <= ~5.3 over N(0,1); shift 6*|a|_1 keeps exp args in [-~30, 0].
        float sh = 6.0f * (fabsf(a.x) + fabsf(a.y) + fabsf(a.z));
        float d = 0.f, s0 = 0.f, s1 = 0.f, s2 = 0.f;
#pragma unroll 4
        for (int jj = 0; jj < 256; ++jj) {
            float4 c = cs[(jj << 2) + sl];
            float sc = fmaf(a.x, c.x, fmaf(a.y, c.y, a.z * c.z));
            float e = __expf(sc - sh);
            d += e;
            s0 = fmaf(e, c.x, s0);
            s1 = fmaf(e, c.y, s1);
            s2 = fmaf(e, c.z, s2);
        }
        d  += __shfl_xor(d, 1);  d  += __shfl_xor(d, 2);
        s0 += __shfl_xor(s0, 1); s0 += __shfl_xor(s0, 2);
        s1 += __shfl_xor(s1, 1); s1 += __shfl_xor(s1, 2);
        s2 += __shfl_xor(s2, 1); s2 += __shfl_xor(s2, 2);
        if (sl == 0) {
            float inv = 1.0f / d;
            cps[qi] = make_float4(s0 * inv, s1 * inv, s2 * inv, 0.f);
        }
    }
    __syncthreads();

    // ---- epilogue: rank-3 + bias, store, GroupNorm partial stats ----
    const floatx4* G4 = (const floatx4*)(ws + WS_G4);
    float4 cpv[4];
#pragma unroll
    for (int ti = 0; ti < 4; ++ti) cpv[ti] = cps[ti * 16 + m];
    float lsum = 0.f, lssq = 0.f;
#pragma unroll
    for (int to = 0; to < 4; ++to)
#pragma unroll
        for (int r = 0; r < 4; ++r) {
            int o = w * 64 + to * 16 + quad * 4 + r;
            floatx4 g = G4[o];
            float* orow = out + (((size_t)(b * 256 + o)) << 10) + i0 + m;
#pragma unroll
            for (int ti = 0; ti < 4; ++ti) {
                float v = acc[to][ti][r]
                        + g[0] * cpv[ti].x + g[1] * cpv[ti].y + g[2] * cpv[ti].z + g[3];
                orow[ti * 16] = v;
                lsum += v; lssq = fmaf(v, v, lssq);
            }
        }
#pragma unroll
    for (int off = 32; off > 0; off >>= 1) {
        lsum += __shfl_down(lsum, off);
        lssq += __shfl_down(lssq, off);
    }
    if (lane == 0) {
        atomicAdd(ws + WS_BSUM + b, lsum);
        atomicAdd(ws + WS_BSSQ + b, lssq);
    }
}

// ---------- K2: GroupNorm(1 group) normalize in place ----------
__global__ __launch_bounds__(256) void sca_norm(float* __restrict__ out,
                                                const float* __restrict__ ws,
                                                const float* __restrict__ gamma,
                                                const float* __restrict__ beta)
{
    size_t idx = (size_t)blockIdx.x * 256 + threadIdx.x;  // float4 index
    float4 v = ((const float4*)out)[idx];
    size_t base = idx << 2;
    int b = (int)(base >> 18);
    int o = (int)((base >> 10) & 255);
    const float inv_n = 1.0f / 262144.0f;
    float mean = ws[WS_BSUM + b] * inv_n;
    float var  = fmaf(ws[WS_BSSQ + b], inv_n, -mean * mean);
    float rs = rsqrtf(var + 1e-5f);
    float ga = gamma[o] * rs;
    float be = fmaf(-mean, ga, beta[o]);
    v.x = fmaf(v.x, ga, be);
    v.y = fmaf(v.y, ga, be);
    v.z = fmaf(v.z, ga, be);
    v.w = fmaf(v.w, ga, be);
    ((float4*)out)[idx] = v;
}

extern "C" void kernel_launch(void* const* d_in, const int* in_sizes, int n_in,
                              void* d_out, int out_size, void* d_ws, size_t ws_size,
                              hipStream_t stream)
{
    const float* Q     = (const float*)d_in[0];
    const float* ctxf  = (const float*)d_in[1];
    const float* Wq    = (const float*)d_in[2];
    const float* bq    = (const float*)d_in[3];
    const float* Wk    = (const float*)d_in[4];
    const float* bk    = (const float*)d_in[5];
    const float* Wv    = (const float*)d_in[6];
    const float* bv    = (const float*)d_in[7];
    const float* Wp    = (const float*)d_in[8];
    const float* bp    = (const float*)d_in[9];
    const float* gamma = (const float*)d_in[10];
    const float* beta  = (const float*)d_in[11];
    float* ws  = (float*)d_ws;
    float* out = (float*)d_out;

    sca_pre  <<<164,  256, 0, stream>>>(Wq, bq, Wk, bk, Wv, bv, Wp, bp, ctxf, ws);
    sca_fused<<<512,  256, 0, stream>>>(Q, ws, out);
    sca_norm <<<8192, 256, 0, stream>>>(out, ws, gamma, beta);
}

// Round 4
// 165.624 us; speedup vs baseline: 1.1347x; 1.1320x over previous
//
#include <hip/hip_runtime.h>
#include <hip/hip_bf16.h>

// B=32, CQ=256, CC=3, COUT=256, H=W=32, HW=1024, INTER=128
//
// Math (verified rounds 0-5, absmax 0.031):
//   scores[i,j] = a[:,i]·ctx[:,j] + c_i (softmax-invariant const dropped)
//     a = M·Q + m0, M = Wk^T Wq (3x256)
//   fused = Wp·Q + G·cp + g0;  G = Wp·Wv (256x3), cp[t,i] = sum_j ctx[t,j]P[i,j]
//   resize 224->32 half-pixel = exact gather at (7y+3, 7x+3).
//
// R9: R8 post-mortem -- two-half staging spilled (FETCH 58/WRITE 108 MB
// phantom scratch traffic; acc64 + qv32 under 128-reg cap) and occupancy
// FELL to 17%. Revert to R6's proven dataflow (i-tile 64, single 32 KB QL,
// load-consume Q loop, 88 VGPR no spill, 60us) and lift 2->3 blocks/CU by
// an LDS diet only: ctx tile as 3 float channels (16->12 KB, broadcast
// reads), cps unioned onto red. LDS 57.9 -> ~52.2 KB; launch_bounds(256,3)
// (reg cap 170 > 152 used). sca_norm trimmed to 2048 grid-stride blocks.
//
// Workspace (float offsets):
#define WS_M     0        // M[3][256], m0[3] at 768
#define WS_G4    1024     // G4[o] = {G0,G1,G2,g0}
#define WS_BSUM  2048     // [32]
#define WS_BSSQ  2080     // [32]
#define WS_WPB   2176     // Wp bf16 fragment-packed [o_tile16][kt8][lane64][8]
#define WS_CTX   34944    // float4 {c0,c1,c2,0} [b 32][j 1024]  (512 KB)

typedef __attribute__((ext_vector_type(8))) short short8;
typedef __attribute__((ext_vector_type(4))) float floatx4;

__device__ inline unsigned short f2bf(float x) {
    unsigned u = __float_as_uint(x);
    return (unsigned short)((u + 0x7FFFu + ((u >> 16) & 1u)) >> 16);
}

// ---------- K0: weight precompute + Wp fragment-pack + ctx pre-gather ----------
// blocks 0..3: M = Wk^T Wq quarters; block 0 also bias + stats zero
// blocks 4..35: Wp bf16 pack + G = Wp*Wv via lane reduction
// blocks 36..163: ctx bilinear-gather -> ws (fully parallel, latency-hidden)
__global__ __launch_bounds__(256) void sca_pre(
    const float* __restrict__ Wq, const float* __restrict__ bq,
    const float* __restrict__ Wk, const float* __restrict__ bk,
    const float* __restrict__ Wv, const float* __restrict__ bv,
    const float* __restrict__ Wp, const float* __restrict__ bp,
    const float* __restrict__ ctxin, float* __restrict__ ws)
{
    int tid = threadIdx.x;
    int blk = blockIdx.x;
    if (blk < 4) {
        __shared__ float WkL[384];
        __shared__ float bqL[128];
        __shared__ float redM[4][64][3];
        int o0 = blk << 6;
        if (tid < 128) bqL[tid] = bq[tid];
        for (int idx = tid; idx < 384; idx += 256) WkL[idx] = Wk[idx];
        __syncthreads();
        int o64 = tid & 63, cg = tid >> 6;
        float m0v = 0.f, m1v = 0.f, m2v = 0.f;
        for (int c0 = cg * 32; c0 < cg * 32 + 32; c0 += 16) {
            float q[16];
#pragma unroll
            for (int j = 0; j < 16; ++j) q[j] = Wq[(c0 + j) * 256 + o0 + o64];
#pragma unroll
            for (int j = 0; j < 16; ++j) {
                int c = c0 + j;
                m0v = fmaf(WkL[c * 3 + 0], q[j], m0v);
                m1v = fmaf(WkL[c * 3 + 1], q[j], m1v);
                m2v = fmaf(WkL[c * 3 + 2], q[j], m2v);
            }
        }
        redM[cg][o64][0] = m0v; redM[cg][o64][1] = m1v; redM[cg][o64][2] = m2v;
        __syncthreads();
        if (tid < 64) {
            float r0 = redM[0][tid][0] + redM[1][tid][0] + redM[2][tid][0] + redM[3][tid][0];
            float r1 = redM[0][tid][1] + redM[1][tid][1] + redM[2][tid][1] + redM[3][tid][1];
            float r2 = redM[0][tid][2] + redM[1][tid][2] + redM[2][tid][2] + redM[3][tid][2];
            ws[WS_M + 0   + o0 + tid] = r0;
            ws[WS_M + 256 + o0 + tid] = r1;
            ws[WS_M + 512 + o0 + tid] = r2;
        }
        if (blk == 0) {
            if (tid < 3) {
                float s = 0.f;
                for (int c = 0; c < 128; ++c) s = fmaf(WkL[c * 3 + tid], bqL[c], s);
                ws[WS_M + 768 + tid] = s;
            }
            if (tid < 64) ws[WS_BSUM + tid] = 0.f;   // bsum[32]+bssq[32]
        }
    } else if (blk < 36) {
        __shared__ float WvL[768];
        __shared__ float bvL[256];
        for (int idx = tid; idx < 768; idx += 256) WvL[idx] = Wv[idx];
        bvL[tid] = bv[tid];
        __syncthreads();
        int idx = (blk - 4) * 2048 + tid * 8;       // flat [o][k] element index
        int o = idx >> 8;
        int kt = (tid & 31) >> 2, quad = tid & 3;
        const float4* s = (const float4*)(Wp + idx);
        float4 x0 = s[0], x1 = s[1];
        uint4 v;
        v.x = (unsigned)f2bf(x0.x) | ((unsigned)f2bf(x0.y) << 16);
        v.y = (unsigned)f2bf(x0.z) | ((unsigned)f2bf(x0.w) << 16);
        v.z = (unsigned)f2bf(x1.x) | ((unsigned)f2bf(x1.y) << 16);
        v.w = (unsigned)f2bf(x1.z) | ((unsigned)f2bf(x1.w) << 16);
        int slot = (((o >> 4) * 8 + kt) * 64) + quad * 16 + (o & 15);
        ((uint4*)((unsigned short*)(ws + WS_WPB)))[slot] = v;
        // G partials over this thread's 8 c; reduce over the 32 lanes sharing o
        int c0 = idx & 255;
        float xv[8] = {x0.x, x0.y, x0.z, x0.w, x1.x, x1.y, x1.z, x1.w};
        float g0 = 0.f, g1 = 0.f, g2 = 0.f, gb = 0.f;
#pragma unroll
        for (int j = 0; j < 8; ++j) {
            int c = c0 + j;
            g0 = fmaf(xv[j], WvL[c * 3 + 0], g0);
            g1 = fmaf(xv[j], WvL[c * 3 + 1], g1);
            g2 = fmaf(xv[j], WvL[c * 3 + 2], g2);
            gb = fmaf(xv[j], bvL[c], gb);
        }
#pragma unroll
        for (int off = 1; off < 32; off <<= 1) {
            g0 += __shfl_xor(g0, off);
            g1 += __shfl_xor(g1, off);
            g2 += __shfl_xor(g2, off);
            gb += __shfl_xor(gb, off);
        }
        if ((tid & 31) == 0)
            ((float4*)(ws + WS_G4))[o] = make_float4(g0, g1, g2, gb + bp[o]);
    } else {
        // ctx gather: one thread per (b, j)
        int g = (blk - 36) * 256 + tid;             // [0, 32768)
        int b = g >> 10, j = g & 1023;
        int y = j >> 5, x = j & 31;
        const float* src = ctxin + (size_t)b * 150528;
        int p = (7 * y + 3) * 224 + (7 * x + 3);
        ((float4*)(ws + WS_CTX))[g] =
            make_float4(src[p], src[p + 50176], src[p + 100352], 0.f);
    }
}

// ---------- K1: fused conv+attn+gemm. 512 blocks = b(32) x i-tile(16 of 64).
// R6 dataflow, LDS 52.2 KB -> 3 blocks/CU. Phases: ctx/Ms stage; Q load +
// a-partials + bf16 pack -> swizzled QL; MFMA K-loop; a-reduce; softmax+cp;
// epilogue rank-3 + bias + stats + store. ----------
__global__ __launch_bounds__(256, 3) void sca_fused(const float* __restrict__ Q,
                                                    float* __restrict__ ws,
                                                    float* __restrict__ out)
{
    __shared__ float Ms[771];
    __shared__ float cs0[1024];           // ctx channel 0
    __shared__ float cs1[1024];           // ctx channel 1
    __shared__ float cs2[1024];           // ctx channel 2
    __shared__ uint4 QL[2048];            // 64 rows x 32 16B-groups, XOR-swizzled
    __shared__ float red[4][16][12];      // [wave][iq][t*4+e]; aliased by cps
    __shared__ float4 av4[64];
    float4* cps = (float4*)red;           // cps[64] reuses red after av4 built

    int tid = threadIdx.x;
    int blk = blockIdx.x;
    int b  = blk >> 4;
    int i0 = (blk & 15) << 6;

    // ctx copy from pre-gathered ws (coalesced float4 read; 3-channel LDS)
    {
        const float4* cg4 = ((const float4*)(ws + WS_CTX)) + ((size_t)b << 10);
#pragma unroll
        for (int s4 = 0; s4 < 4; ++s4) {
            int j = s4 * 256 + tid;
            float4 v = cg4[j];
            cs0[j] = v.x; cs1[j] = v.y; cs2[j] = v.z;
        }
    }
    for (int idx = tid; idx < 771; idx += 256) Ms[idx] = ws[WS_M + idx];
    __syncthreads();

    // ---- Q load + a-partials + bf16 pack (load-consume, no batching: R8's
    // register batch under a reg cap spilled; this form measured 88 VGPR) ----
    int iq = tid & 15, kg = tid >> 4;      // 4 consecutive i x 16 consecutive k
    const float* Qp = Q + ((size_t)b << 18) + ((size_t)(kg * 16) << 10) + i0 + iq * 4;
    float a00=0.f,a01=0.f,a02=0.f,a03=0.f;
    float a10=0.f,a11=0.f,a12=0.f,a13=0.f;
    float a20=0.f,a21=0.f,a22=0.f,a23=0.f;
    unsigned pk[4][8];                     // [e][pair]: bf16 of k = kg*16 + 2*pair(+1)
#pragma unroll
    for (int s = 0; s < 16; ++s) {
        float4 qv = *(const float4*)(Qp + ((size_t)s << 10));
        int c = kg * 16 + s;
        float m0 = Ms[c], m1 = Ms[256 + c], m2 = Ms[512 + c];
        a00 = fmaf(m0, qv.x, a00); a01 = fmaf(m0, qv.y, a01); a02 = fmaf(m0, qv.z, a02); a03 = fmaf(m0, qv.w, a03);
        a10 = fmaf(m1, qv.x, a10); a11 = fmaf(m1, qv.y, a11); a12 = fmaf(m1, qv.z, a12); a13 = fmaf(m1, qv.w, a13);
        a20 = fmaf(m2, qv.x, a20); a21 = fmaf(m2, qv.y, a21); a22 = fmaf(m2, qv.z, a22); a23 = fmaf(m2, qv.w, a23);
        unsigned h0 = f2bf(qv.x), h1 = f2bf(qv.y), h2 = f2bf(qv.z), h3 = f2bf(qv.w);
        int j = s >> 1;
        if (s & 1) {
            pk[0][j] |= h0 << 16; pk[1][j] |= h1 << 16;
            pk[2][j] |= h2 << 16; pk[3][j] |= h3 << 16;
        } else {
            pk[0][j] = h0; pk[1][j] = h1; pk[2][j] = h2; pk[3][j] = h3;
        }
    }
    // B-fragments into swizzled LDS: row = local i, 16B-group g = k-octet.
    // swizzle s=(row^(row>>3))&7 on low 3 bits of g: conflict-free writes+reads.
#pragma unroll
    for (int e = 0; e < 4; ++e) {
        int row = iq * 4 + e;
        int sw = (row ^ (row >> 3)) & 7;
#pragma unroll
        for (int h = 0; h < 2; ++h) {
            int g = kg * 2 + h;
            int gs = (g & 24) | ((g ^ sw) & 7);
            QL[row * 32 + gs] =
                make_uint4(pk[e][h*4+0], pk[e][h*4+1], pk[e][h*4+2], pk[e][h*4+3]);
        }
    }
    // a-reduction over kg: lanes iq, iq+16, iq+32, iq+48 share iq within a wave
    a00 += __shfl_xor(a00,16); a00 += __shfl_xor(a00,32);
    a01 += __shfl_xor(a01,16); a01 += __shfl_xor(a01,32);
    a02 += __shfl_xor(a02,16); a02 += __shfl_xor(a02,32);
    a03 += __shfl_xor(a03,16); a03 += __shfl_xor(a03,32);
    a10 += __shfl_xor(a10,16); a10 += __shfl_xor(a10,32);
    a11 += __shfl_xor(a11,16); a11 += __shfl_xor(a11,32);
    a12 += __shfl_xor(a12,16); a12 += __shfl_xor(a12,32);
    a13 += __shfl_xor(a13,16); a13 += __shfl_xor(a13,32);
    a20 += __shfl_xor(a20,16); a20 += __shfl_xor(a20,32);
    a21 += __shfl_xor(a21,16); a21 += __shfl_xor(a21,32);
    a22 += __shfl_xor(a22,16); a22 += __shfl_xor(a22,32);
    a23 += __shfl_xor(a23,16); a23 += __shfl_xor(a23,32);
    int lane = tid & 63, w = tid >> 6;
    if (lane < 16) {
        red[w][lane][0]=a00; red[w][lane][1]=a01; red[w][lane][2] =a02; red[w][lane][3] =a03;
        red[w][lane][4]=a10; red[w][lane][5]=a11; red[w][lane][6] =a12; red[w][lane][7] =a13;
        red[w][lane][8]=a20; red[w][lane][9]=a21; red[w][lane][10]=a22; red[w][lane][11]=a23;
    }
    __syncthreads();
    if (tid < 64) {
        int iqq = tid >> 2, e = tid & 3;
        float r0 = red[0][iqq][0+e] + red[1][iqq][0+e] + red[2][iqq][0+e] + red[3][iqq][0+e] + Ms[768];
        float r1 = red[0][iqq][4+e] + red[1][iqq][4+e] + red[2][iqq][4+e] + red[3][iqq][4+e] + Ms[769];
        float r2 = red[0][iqq][8+e] + red[1][iqq][8+e] + red[2][iqq][8+e] + red[3][iqq][8+e] + Ms[770];
        av4[tid] = make_float4(r0, r1, r2, 0.f);
    }
    __syncthreads();

    // ---- MFMA K-loop: wave w covers o = w*64..w*64+63, all i of this block ----
    int m = lane & 15, quad = lane >> 4;
    const short8* Apack = (const short8*)((const unsigned short*)(ws + WS_WPB));
    const short8* QLs = (const short8*)QL;
    floatx4 acc[4][4] = {};
#pragma unroll
    for (int kt = 0; kt < 8; ++kt) {
        short8 af[4], bf[4];
#pragma unroll
        for (int t = 0; t < 4; ++t)
            af[t] = Apack[((w * 4 + t) * 8 + kt) * 64 + lane];
#pragma unroll
        for (int t = 0; t < 4; ++t) {
            int row = t * 16 + m;
            int sw = (row ^ (row >> 3)) & 7;
            int g = kt * 4 + quad;
            int gs = (g & 24) | ((g ^ sw) & 7);
            bf[t] = QLs[row * 32 + gs];
        }
#pragma unroll
        for (int to = 0; to < 4; ++to)
#pragma unroll
            for (int ti = 0; ti < 4; ++ti)
                acc[to][ti] = __builtin_amdgcn_mfma_f32_16x16x32_bf16(
                    af[to], bf[ti], acc[to][ti], 0, 0, 0);
    }

    // ---- softmax + cp (4 lanes per query i, single pass, analytic shift) ----
    {
        int qi = tid >> 2, sl = tid & 3;
        float4 a = av4[qi];
        // |ctx| <= ~5.3 over N(0,1); shift 6*|a|_1 keeps exp args in [-~30, 0].
        float sh = 6.0f * (fabsf(a.x) + fabsf(a.y) + fabsf(a.z));
        float d = 0.f, s0 = 0.f, s1 = 0.f, s2 = 0.f;
#pragma unroll 4
        for (int jj = 0; jj < 256; ++jj) {
            int j = (jj << 2) + sl;
            float c0 = cs0[j], c1 = cs1[j], c2 = cs2[j];   // broadcast reads
            float sc = fmaf(a.x, c0, fmaf(a.y, c1, a.z * c2));
            float e = __expf(sc - sh);
            d += e;
            s0 = fmaf(e, c0, s0);
            s1 = fmaf(e, c1, s1);
            s2 = fmaf(e, c2, s2);
        }
        d  += __shfl_xor(d, 1);  d  += __shfl_xor(d, 2);
        s0 += __shfl_xor(s0, 1); s0 += __shfl_xor(s0, 2);
        s1 += __shfl_xor(s1, 1); s1 += __shfl_xor(s1, 2);
        s2 += __shfl_xor(s2, 1); s2 += __shfl_xor(s2, 2);
        if (sl == 0) {
            float inv = 1.0f / d;
            cps[qi] = make_float4(s0 * inv, s1 * inv, s2 * inv, 0.f);
        }
    }
    __syncthreads();

    // ---- epilogue: rank-3 + bias, store, GroupNorm partial stats ----
    const floatx4* G4 = (const floatx4*)(ws + WS_G4);
    float4 cpv[4];
#pragma unroll
    for (int ti = 0; ti < 4; ++ti) cpv[ti] = cps[ti * 16 + m];
    float lsum = 0.f, lssq = 0.f;
#pragma unroll
    for (int to = 0; to < 4; ++to)
#pragma unroll
        for (int r = 0; r < 4; ++r) {
            int o = w * 64 + to * 16 + quad * 4 + r;
            floatx4 g = G4[o];
            float* orow = out + (((size_t)(b * 256 + o)) << 10) + i0 + m;
#pragma unroll
            for (int ti = 0; ti < 4; ++ti) {
                float v = acc[to][ti][r]
                        + g[0] * cpv[ti].x + g[1] * cpv[ti].y + g[2] * cpv[ti].z + g[3];
                orow[ti * 16] = v;
                lsum += v; lssq = fmaf(v, v, lssq);
            }
        }
#pragma unroll
    for (int off = 32; off > 0; off >>= 1) {
        lsum += __shfl_down(lsum, off);
        lssq += __shfl_down(lssq, off);
    }
    if (lane == 0) {
        atomicAdd(ws + WS_BSUM + b, lsum);
        atomicAdd(ws + WS_BSSQ + b, lssq);
    }
}

// ---------- K2: GroupNorm(1 group) normalize in place (grid-stride x4) ----------
__global__ __launch_bounds__(256) void sca_norm(float* __restrict__ out,
                                                const float* __restrict__ ws,
                                                const float* __restrict__ gamma,
                                                const float* __restrict__ beta)
{
    const float inv_n = 1.0f / 262144.0f;
#pragma unroll
    for (int r = 0; r < 4; ++r) {
        size_t idx = (size_t)r * 524288 + (size_t)blockIdx.x * 256 + threadIdx.x;
        float4 v = ((const float4*)out)[idx];
        size_t base = idx << 2;
        int b = (int)(base >> 18);
        int o = (int)((base >> 10) & 255);
        float mean = ws[WS_BSUM + b] * inv_n;
        float var  = fmaf(ws[WS_BSSQ + b], inv_n, -mean * mean);
        float rs = rsqrtf(var + 1e-5f);
        float ga = gamma[o] * rs;
        float be = fmaf(-mean, ga, beta[o]);
        v.x = fmaf(v.x, ga, be);
        v.y = fmaf(v.y, ga, be);
        v.z = fmaf(v.z, ga, be);
        v.w = fmaf(v.w, ga, be);
        ((float4*)out)[idx] = v;
    }
}

extern "C" void kernel_launch(void* const* d_in, const int* in_sizes, int n_in,
                              void* d_out, int out_size, void* d_ws, size_t ws_size,
                              hipStream_t stream)
{
    const float* Q     = (const float*)d_in[0];
    const float* ctxf  = (const float*)d_in[1];
    const float* Wq    = (const float*)d_in[2];
    const float* bq    = (const float*)d_in[3];
    const float* Wk    = (const float*)d_in[4];
    const float* bk    = (const float*)d_in[5];
    const float* Wv    = (const float*)d_in[6];
    const float* bv    = (const float*)d_in[7];
    const float* Wp    = (const float*)d_in[8];
    const float* bp    = (const float*)d_in[9];
    const float* gamma = (const float*)d_in[10];
    const float* beta  = (const float*)d_in[11];
    float* ws  = (float*)d_ws;
    float* out = (float*)d_out;

    sca_pre  <<<164,  256, 0, stream>>>(Wq, bq, Wk, bk, Wv, bv, Wp, bp, ctxf, ws);
    sca_fused<<<512,  256, 0, stream>>>(Q, ws, out);
    sca_norm <<<2048, 256, 0, stream>>>(out, ws, gamma, beta);
}